// Round 3
// baseline (491.854 us; speedup 1.0000x reference)
//
#include <hip/hip_runtime.h>
#include <math.h>

#define N_NODES_C 8000
#define N_EDGES_C 64000

static constexpr float PW0_C     = 0.14433756729740646f;   // sqrt(1/48)
static constexpr float C1_C      = 0.14433756729740643f;   // PW1 * INV_SQRT3
static constexpr float PW0IS3_C  = 0.08333333333333333f;   // PW0 * INV_SQRT3
static constexpr float RS32_C    = 0.17677669529663687f;   // 1/sqrt(32)

__device__ __forceinline__ float silu_f(float x) { return x / (1.0f + expf(-x)); }

// One block = 64 edges. Fused: radial MLP -> tpw GEMM (chunked) -> TP contraction -> atomic scatter.
// NOTE: edge_index arrives as int32 (harness converts all integer inputs to int).
__global__ __launch_bounds__(256, 1) void edge_kernel(
    const float* __restrict__ nf,
    const int*   __restrict__ ei,
    const float* __restrict__ sh,
    const float* __restrict__ emb,
    const float* __restrict__ rW1,
    const float* __restrict__ rb1,
    const float* __restrict__ rW2,
    const float* __restrict__ rb2,
    float* __restrict__ agg)
{
    __shared__ float hT[64][68];     // hT[c][e], padded
    __shared__ float tpw[64][132];   // tpw[e][j within chunk], padded
    __shared__ float xs_s[64][32];
    __shared__ float xv_s[64][48];
    __shared__ float dv_s[64][16];
    __shared__ float sh0_s[64];
    __shared__ float shv_s[64][3];
    __shared__ int   dst_s[64];
    __shared__ float msg[64][84];

    const int t  = threadIdx.x;
    const int e0 = blockIdx.x * 64;

    if (t < 64) {
        const int eid = e0 + t;
        dst_s[t] = ei[N_EDGES_C + eid];
        const float4 s4 = *reinterpret_cast<const float4*>(sh + (size_t)eid * 4);
        sh0_s[t] = s4.x;
        shv_s[t][0] = s4.y; shv_s[t][1] = s4.z; shv_s[t][2] = s4.w;
    }
    for (int i = t; i < 64 * 84; i += 256) (&msg[0][0])[i] = 0.0f;

    // Gather node features for the 64 source nodes (4 threads/edge, 20 floats each)
    {
        const int e = t >> 2, q = t & 3;
        const int src = ei[e0 + e];
        const float* p = nf + (size_t)src * 80 + q * 20;
        #pragma unroll
        for (int f4 = 0; f4 < 5; f4++) {
            const float4 v = *reinterpret_cast<const float4*>(p + f4 * 4);
            const int g = q * 20 + f4 * 4;
            const float vv[4] = {v.x, v.y, v.z, v.w};
            #pragma unroll
            for (int ii = 0; ii < 4; ii++) {
                const int gg = g + ii;
                if (gg < 32) xs_s[e][gg] = vv[ii];
                else         xv_s[e][gg - 32] = vv[ii];
            }
        }
    }

    // Radial hidden: h[e][c] = silu(emb[e] . rW1[:,c] + rb1[c]), stored transposed
    {
        const int c = t & 63, eg = t >> 6;
        float w1[8];
        #pragma unroll
        for (int b = 0; b < 8; b++) w1[b] = rW1[b * 64 + c];
        const float bias = rb1[c];
        #pragma unroll
        for (int rep = 0; rep < 16; rep++) {
            const int e = rep * 4 + eg;
            const float* em = emb + (size_t)(e0 + e) * 8;
            float pre = bias;
            #pragma unroll
            for (int b = 0; b < 8; b++) pre = fmaf(em[b], w1[b], pre);
            hT[c][e] = silu_f(pre);
        }
    }
    __syncthreads();

    // dv[e][u] = xv[e][u][:] . shv[e][:]
    {
        const int e = t >> 2, q = t & 3;
        #pragma unroll
        for (int i = 0; i < 4; i++) {
            const int u = q * 4 + i;
            dv_s[e][u] = xv_s[e][u*3+0]*shv_s[e][0] + xv_s[e][u*3+1]*shv_s[e][1]
                       + xv_s[e][u*3+2]*shv_s[e][2];
        }
    }
    __syncthreads();

    // 18 chunks of 128 columns: GEMM (M=64,N=128,K=64) then segment epilogue
    const int lane = t & 63;   // 2 cols each -> 128
    const int wv   = t >> 6;   // wave id -> 16 edges each
    for (int ch = 0; ch < 18; ch++) {
        const int jb = ch * 128;
        float acc[16][2];
        #pragma unroll
        for (int i = 0; i < 16; i++) { acc[i][0] = 0.0f; acc[i][1] = 0.0f; }

        const float* Bp = rW2 + jb + lane * 2;
        #pragma unroll 2
        for (int c = 0; c < 64; c++) {
            const float2 b = *reinterpret_cast<const float2*>(Bp + (size_t)c * 2304);
            const float4* ap = reinterpret_cast<const float4*>(&hT[c][wv * 16]);
            const float4 a0 = ap[0], a1 = ap[1], a2 = ap[2], a3 = ap[3];
            const float va[16] = {a0.x,a0.y,a0.z,a0.w, a1.x,a1.y,a1.z,a1.w,
                                  a2.x,a2.y,a2.z,a2.w, a3.x,a3.y,a3.z,a3.w};
            #pragma unroll
            for (int i = 0; i < 16; i++) {
                acc[i][0] = fmaf(va[i], b.x, acc[i][0]);
                acc[i][1] = fmaf(va[i], b.y, acc[i][1]);
            }
        }

        const float2 rb = *reinterpret_cast<const float2*>(rb2 + jb + lane * 2);
        __syncthreads();   // previous epilogue finished reading tpw
        #pragma unroll
        for (int i = 0; i < 16; i++) {
            *reinterpret_cast<float2*>(&tpw[wv * 16 + i][lane * 2]) =
                make_float2(acc[i][0] + rb.x, acc[i][1] + rb.y);
        }
        __syncthreads();

        if (ch < 8) {                       // A segment: u0 = ch*4
            const int u0 = ch * 4;
            const int w = t & 31, eg = t >> 5;
            #pragma unroll
            for (int ee = 0; ee < 8; ee++) {
                const int e = eg * 8 + ee;
                float s = 0.0f;
                #pragma unroll
                for (int du = 0; du < 4; du++)
                    s = fmaf(tpw[e][du * 32 + w], xs_s[e][u0 + du], s);
                msg[e][w] = fmaf(PW0_C * sh0_s[e], s, msg[e][w]);
            }
        } else if (ch < 12) {               // B segment: u0 = (ch-8)*8
            const int u0 = (ch - 8) * 8;
            const int w = t & 15, eg = t >> 4;
            #pragma unroll
            for (int ee = 0; ee < 4; ee++) {
                const int e = eg * 4 + ee;
                float s = 0.0f;
                #pragma unroll
                for (int du = 0; du < 8; du++)
                    s = fmaf(tpw[e][du * 16 + w], xs_s[e][u0 + du], s);
                const float c1s = C1_C * s;
                msg[e][32 + w*3 + 0] = fmaf(c1s, shv_s[e][0], msg[e][32 + w*3 + 0]);
                msg[e][32 + w*3 + 1] = fmaf(c1s, shv_s[e][1], msg[e][32 + w*3 + 1]);
                msg[e][32 + w*3 + 2] = fmaf(c1s, shv_s[e][2], msg[e][32 + w*3 + 2]);
            }
        } else if (ch < 14) {               // C segment: u0 = (ch-12)*8
            const int u0 = (ch - 12) * 8;
            const int w = t & 15, eg = t >> 4;
            #pragma unroll
            for (int ee = 0; ee < 4; ee++) {
                const int e = eg * 4 + ee;
                float s0 = 0.0f, s1 = 0.0f, s2 = 0.0f;
                #pragma unroll
                for (int du = 0; du < 8; du++) {
                    const float tv = tpw[e][du * 16 + w];
                    const int u = u0 + du;
                    s0 = fmaf(tv, xv_s[e][u*3 + 0], s0);
                    s1 = fmaf(tv, xv_s[e][u*3 + 1], s1);
                    s2 = fmaf(tv, xv_s[e][u*3 + 2], s2);
                }
                const float f = C1_C * sh0_s[e];
                msg[e][32 + w*3 + 0] = fmaf(f, s0, msg[e][32 + w*3 + 0]);
                msg[e][32 + w*3 + 1] = fmaf(f, s1, msg[e][32 + w*3 + 1]);
                msg[e][32 + w*3 + 2] = fmaf(f, s2, msg[e][32 + w*3 + 2]);
            }
        } else {                            // D segment: u0 = (ch-14)*4
            const int u0 = (ch - 14) * 4;
            const int w = t & 31, eg = t >> 5;
            #pragma unroll
            for (int ee = 0; ee < 8; ee++) {
                const int e = eg * 8 + ee;
                float s = 0.0f;
                #pragma unroll
                for (int du = 0; du < 4; du++)
                    s = fmaf(tpw[e][du * 32 + w], dv_s[e][u0 + du], s);
                msg[e][w] = fmaf(PW0IS3_C, s, msg[e][w]);
            }
        }
    }

    __syncthreads();
    for (int i = t; i < 64 * 80; i += 256) {
        const int e = i / 80, m = i - e * 80;
        atomicAdd(&agg[(size_t)dst_s[e] * 80 + m], msg[e][m]);
    }
}

// Node update, IN PLACE on io (= d_out, which holds agg after edge_kernel).
// Each block owns 4 node rows: stage them in LDS, sync, then overwrite.
__global__ __launch_bounds__(256, 4) void node_kernel(
    const float* __restrict__ nf,
    float* __restrict__ io,
    const float* __restrict__ Wl0,
    const float* __restrict__ Wl1)
{
    __shared__ float a_s[4][80];
    const int t  = threadIdx.x;
    const int nb = blockIdx.x * 4;
    for (int i = t; i < 320; i += 256)            // FIX: 256 threads must cover 320 floats
        a_s[i / 80][i % 80] = io[(size_t)nb * 80 + i];
    __syncthreads();

    const int ln = t >> 6;          // local node 0..3
    const int r  = t & 63;
    const int n  = nb + ln;
    const float* a = a_s[ln];
    if (r < 32) {
        float s = 0.0f;
        #pragma unroll
        for (int u = 0; u < 32; u++) s = fmaf(a[u], Wl0[u * 32 + r], s);
        s *= RS32_C;
        io[(size_t)n * 80 + r] = nf[(size_t)n * 80 + r] + silu_f(s);
    } else if (r < 48) {
        const int v = r - 32;
        float l0 = 0.0f, l1 = 0.0f, l2 = 0.0f;
        #pragma unroll
        for (int u = 0; u < 16; u++) {
            const float w = Wl1[u * 16 + v];
            l0 = fmaf(a[32 + u*3 + 0], w, l0);
            l1 = fmaf(a[32 + u*3 + 1], w, l1);
            l2 = fmaf(a[32 + u*3 + 2], w, l2);
        }
        l0 *= 0.25f; l1 *= 0.25f; l2 *= 0.25f;
        const float norm = sqrtf(l0*l0 + l1*l1 + l2*l2);
        float f = 0.0f;
        if (norm >= 1e-8f) f = silu_f(norm) / norm;
        const size_t o = (size_t)n * 80 + 32 + (size_t)v * 3;
        io[o + 0] = nf[o + 0] + f * l0;
        io[o + 1] = nf[o + 1] + f * l1;
        io[o + 2] = nf[o + 2] + f * l2;
    }
}

extern "C" void kernel_launch(void* const* d_in, const int* in_sizes, int n_in,
                              void* d_out, int out_size, void* d_ws, size_t ws_size,
                              hipStream_t stream) {
    const float* nf  = (const float*)d_in[0];
    const int*   ei  = (const int*)d_in[1];     // harness passes integer inputs as int32
    const float* sh  = (const float*)d_in[2];
    const float* emb = (const float*)d_in[3];
    const float* rW1 = (const float*)d_in[4];
    const float* rb1 = (const float*)d_in[5];
    const float* rW2 = (const float*)d_in[6];
    const float* rb2 = (const float*)d_in[7];
    const float* Wl0 = (const float*)d_in[8];
    const float* Wl1 = (const float*)d_in[9];

    float* agg = (float*)d_out;   // accumulate messages directly in d_out (no ws_size dependence)
    hipMemsetAsync(agg, 0, (size_t)N_NODES_C * 80 * sizeof(float), stream);
    edge_kernel<<<N_EDGES_C / 64, 256, 0, stream>>>(nf, ei, sh, emb, rW1, rb1, rW2, rb2, agg);
    node_kernel<<<N_NODES_C / 4, 256, 0, stream>>>(nf, agg, Wl0, Wl1);
}

// Round 4
// 217.192 us; speedup vs baseline: 2.2646x; 2.2646x over previous
//
#include <hip/hip_runtime.h>
#include <math.h>

#define N_NODES_C 8000
#define N_EDGES_C 64000

static constexpr float PW0_C     = 0.14433756729740646f;   // sqrt(1/48)
static constexpr float C1_C      = 0.14433756729740643f;   // PW1 * INV_SQRT3
static constexpr float PW0IS3_C  = 0.08333333333333333f;   // PW0 * INV_SQRT3
static constexpr float RS32_C    = 0.17677669529663687f;   // 1/sqrt(32)

typedef __attribute__((ext_vector_type(8))) short short8;
typedef __attribute__((ext_vector_type(4))) float f32x4;

__device__ __forceinline__ float silu_f(float x) { return x / (1.0f + expf(-x)); }

__device__ __forceinline__ unsigned short f2bf(float x) {
    union { float f; unsigned u; } a; a.f = x;
    unsigned r = a.u + 0x7fffu + ((a.u >> 16) & 1u);   // RNE
    return (unsigned short)(r >> 16);
}

// Transpose rW2 (64 x 2304 f32) -> rW2T (2304 x 64 bf16). Coalesced reads.
__global__ __launch_bounds__(256) void prep_kernel(
    const float* __restrict__ rW2, unsigned short* __restrict__ rW2T)
{
    const int idx = blockIdx.x * 256 + threadIdx.x;      // 576 blocks * 256 = 147456
    const int k = idx / 2304, col = idx % 2304;
    rW2T[(size_t)col * 64 + k] = f2bf(rW2[idx]);
}

// MFMA edge kernel: one block = 64 edges, 4 waves.
// radial MLP -> bf16 h in LDS -> MFMA GEMM vs rW2T (global, L2) per 128-col chunk
// -> f32 tpw in LDS -> float4 epilogue accumulating messages in REGISTERS -> atomic scatter.
__global__ __launch_bounds__(256, 2) void edge_kernel_mfma(
    const float* __restrict__ nf,
    const int*   __restrict__ ei,
    const float* __restrict__ sh,
    const float* __restrict__ emb,
    const float* __restrict__ rW1,
    const float* __restrict__ rb1,
    const unsigned short* __restrict__ rW2T,
    const float* __restrict__ rb2,
    float* __restrict__ agg)
{
    __shared__ unsigned short hB[64][72];   // h bf16, [e][k], row 144B (16B mult)
    __shared__ float tpw[64][132];          // f32 chunk of tpw, [e][jloc]
    __shared__ float xs_s[64][33];
    __shared__ float xv_s[64][52];
    __shared__ float dv_s[64][17];
    __shared__ float sh0_s[64];
    __shared__ float shv_s[64][3];
    __shared__ int   dst_s[64];

    const int t    = threadIdx.x;
    const int e0   = blockIdx.x * 64;
    const int lane = t & 63, wv = t >> 6;
    const int l15  = lane & 15, lk = lane >> 4;

    // --- staging ---
    if (t < 64) {
        const int eid = e0 + t;
        dst_s[t] = ei[N_EDGES_C + eid];
        const float4 s4 = *reinterpret_cast<const float4*>(sh + (size_t)eid * 4);
        sh0_s[t] = s4.x;
        shv_s[t][0] = s4.y; shv_s[t][1] = s4.z; shv_s[t][2] = s4.w;
    }
    {   // gather node features (4 threads/edge, 20 floats each)
        const int e = t >> 2, q = t & 3;
        const int src = ei[e0 + e];
        const float* p = nf + (size_t)src * 80 + q * 20;
        #pragma unroll
        for (int f4 = 0; f4 < 5; f4++) {
            const float4 v = *reinterpret_cast<const float4*>(p + f4 * 4);
            const int g = q * 20 + f4 * 4;
            const float vv[4] = {v.x, v.y, v.z, v.w};
            #pragma unroll
            for (int ii = 0; ii < 4; ii++) {
                const int gg = g + ii;
                if (gg < 32) xs_s[e][gg] = vv[ii];
                else         xv_s[e][gg - 32] = vv[ii];
            }
        }
    }
    {   // radial hidden -> bf16 hB[e][k]
        const int c = t & 63, eg = t >> 6;
        float w1[8];
        #pragma unroll
        for (int b = 0; b < 8; b++) w1[b] = rW1[b * 64 + c];
        const float bias = rb1[c];
        #pragma unroll
        for (int rep = 0; rep < 16; rep++) {
            const int e = rep * 4 + eg;
            const float* em = emb + (size_t)(e0 + e) * 8;
            float pre = bias;
            #pragma unroll
            for (int b = 0; b < 8; b++) pre = fmaf(em[b], w1[b], pre);
            hB[e][c] = f2bf(silu_f(pre));
        }
    }
    __syncthreads();
    {   // dv[e][u] = xv[e][u][:] . shv[e][:]
        const int e = t >> 2, q = t & 3;
        #pragma unroll
        for (int i = 0; i < 4; i++) {
            const int u = q * 4 + i;
            dv_s[e][u] = xv_s[e][u*3+0]*shv_s[e][0] + xv_s[e][u*3+1]*shv_s[e][1]
                       + xv_s[e][u*3+2]*shv_s[e][2];
        }
    }
    __syncthreads();

    // register message accumulators (disjoint static ownership)
    float sacc[2][4] = {{0,0,0,0},{0,0,0,0}};   // scalar msg: e in {e0t,e0t+1}, w in w4..w4+3
    float vacc[4][3] = {{0,0,0},{0,0,0},{0,0,0},{0,0,0}}; // vector msg: e=ev, w in w4v..+3, k
    const int w4  = (t & 7) * 4;     const int e0t = (t >> 3) * 2;   // A/D mapping
    const int w4v = (t & 3) * 4;     const int ev  = t >> 2;         // B/C mapping

    for (int ch = 0; ch < 18; ch++) {
        const int jb = ch * 128;
        const int colbase = jb + wv * 32;

        // --- GEMM: 4 M-tiles x 2 N-tiles x 2 K-steps of 16x16x32 ---
        f32x4 acc[4][2];
        #pragma unroll
        for (int m = 0; m < 4; m++) { acc[m][0] = (f32x4)0.0f; acc[m][1] = (f32x4)0.0f; }
        #pragma unroll
        for (int s = 0; s < 2; s++) {
            const int k0 = s * 32 + lk * 8;
            short8 a[4];
            #pragma unroll
            for (int m = 0; m < 4; m++)
                a[m] = *reinterpret_cast<const short8*>(&hB[m * 16 + l15][k0]);
            #pragma unroll
            for (int nt = 0; nt < 2; nt++) {
                const short8 b = *reinterpret_cast<const short8*>(
                    rW2T + (size_t)(colbase + nt * 16 + l15) * 64 + k0);
                #pragma unroll
                for (int m = 0; m < 4; m++)
                    acc[m][nt] = __builtin_amdgcn_mfma_f32_16x16x32_bf16(a[m], b, acc[m][nt], 0, 0, 0);
            }
        }
        const float b0 = rb2[colbase + l15];
        const float b1 = rb2[colbase + 16 + l15];

        __syncthreads();   // previous epilogue finished reading tpw
        #pragma unroll
        for (int m = 0; m < 4; m++)
            #pragma unroll
            for (int nt = 0; nt < 2; nt++) {
                const float bb = nt ? b1 : b0;
                #pragma unroll
                for (int r = 0; r < 4; r++)
                    tpw[m * 16 + lk * 4 + r][wv * 32 + nt * 16 + l15] = acc[m][nt][r] + bb;
            }
        __syncthreads();   // tpw chunk ready

        // --- epilogue: contract this chunk into register accumulators ---
        if (ch < 8) {                        // A: j = u*32+w, u0 = ch*4
            const int u0 = ch * 4;
            #pragma unroll
            for (int ee = 0; ee < 2; ee++) {
                const int e = e0t + ee;
                float s0 = 0, s1 = 0, s2 = 0, s3 = 0;
                #pragma unroll
                for (int du = 0; du < 4; du++) {
                    const float4 v = *reinterpret_cast<const float4*>(&tpw[e][du * 32 + w4]);
                    const float x = xs_s[e][u0 + du];
                    s0 = fmaf(v.x, x, s0); s1 = fmaf(v.y, x, s1);
                    s2 = fmaf(v.z, x, s2); s3 = fmaf(v.w, x, s3);
                }
                const float f = PW0_C * sh0_s[e];
                sacc[ee][0] = fmaf(f, s0, sacc[ee][0]); sacc[ee][1] = fmaf(f, s1, sacc[ee][1]);
                sacc[ee][2] = fmaf(f, s2, sacc[ee][2]); sacc[ee][3] = fmaf(f, s3, sacc[ee][3]);
            }
        } else if (ch < 12) {                // B: j = 1024+u*16+w, u0 = (ch-8)*8
            const int u0 = (ch - 8) * 8;
            float s0 = 0, s1 = 0, s2 = 0, s3 = 0;
            #pragma unroll
            for (int du = 0; du < 8; du++) {
                const float4 v = *reinterpret_cast<const float4*>(&tpw[ev][du * 16 + w4v]);
                const float x = xs_s[ev][u0 + du];
                s0 = fmaf(v.x, x, s0); s1 = fmaf(v.y, x, s1);
                s2 = fmaf(v.z, x, s2); s3 = fmaf(v.w, x, s3);
            }
            const float sq[4] = {s0, s1, s2, s3};
            #pragma unroll
            for (int q = 0; q < 4; q++) {
                const float cs = C1_C * sq[q];
                #pragma unroll
                for (int k = 0; k < 3; k++)
                    vacc[q][k] = fmaf(cs, shv_s[ev][k], vacc[q][k]);
            }
        } else if (ch < 14) {                // C: j = 1536+u*16+w, u0 = (ch-12)*8
            const int u0 = (ch - 12) * 8;
            float sk[3][4] = {{0,0,0,0},{0,0,0,0},{0,0,0,0}};
            #pragma unroll
            for (int du = 0; du < 8; du++) {
                const float4 v = *reinterpret_cast<const float4*>(&tpw[ev][du * 16 + w4v]);
                const float vq[4] = {v.x, v.y, v.z, v.w};
                #pragma unroll
                for (int k = 0; k < 3; k++) {
                    const float xk = xv_s[ev][(u0 + du) * 3 + k];
                    #pragma unroll
                    for (int q = 0; q < 4; q++) sk[k][q] = fmaf(vq[q], xk, sk[k][q]);
                }
            }
            const float f = C1_C * sh0_s[ev];
            #pragma unroll
            for (int q = 0; q < 4; q++)
                #pragma unroll
                for (int k = 0; k < 3; k++)
                    vacc[q][k] = fmaf(f, sk[k][q], vacc[q][k]);
        } else {                             // D: j = 1792+u*32+w, u0 = (ch-14)*4
            const int u0 = (ch - 14) * 4;
            #pragma unroll
            for (int ee = 0; ee < 2; ee++) {
                const int e = e0t + ee;
                float s0 = 0, s1 = 0, s2 = 0, s3 = 0;
                #pragma unroll
                for (int du = 0; du < 4; du++) {
                    const float4 v = *reinterpret_cast<const float4*>(&tpw[e][du * 32 + w4]);
                    const float x = dv_s[e][u0 + du];
                    s0 = fmaf(v.x, x, s0); s1 = fmaf(v.y, x, s1);
                    s2 = fmaf(v.z, x, s2); s3 = fmaf(v.w, x, s3);
                }
                sacc[ee][0] = fmaf(PW0IS3_C, s0, sacc[ee][0]);
                sacc[ee][1] = fmaf(PW0IS3_C, s1, sacc[ee][1]);
                sacc[ee][2] = fmaf(PW0IS3_C, s2, sacc[ee][2]);
                sacc[ee][3] = fmaf(PW0IS3_C, s3, sacc[ee][3]);
            }
        }
    }

    // --- scatter: 20 atomics/thread = minimal 5.12M total ---
    #pragma unroll
    for (int ee = 0; ee < 2; ee++) {
        float* base = agg + (size_t)dst_s[e0t + ee] * 80 + w4;
        #pragma unroll
        for (int q = 0; q < 4; q++) atomicAdd(base + q, sacc[ee][q]);
    }
    {
        float* base = agg + (size_t)dst_s[ev] * 80 + 32 + w4v * 3;
        #pragma unroll
        for (int q = 0; q < 4; q++)
            #pragma unroll
            for (int k = 0; k < 3; k++) atomicAdd(base + q * 3 + k, vacc[q][k]);
    }
}

// ---------------- fallback f32 edge kernel (proven R3) ----------------
__global__ __launch_bounds__(256, 1) void edge_kernel_f32(
    const float* __restrict__ nf, const int* __restrict__ ei,
    const float* __restrict__ sh, const float* __restrict__ emb,
    const float* __restrict__ rW1, const float* __restrict__ rb1,
    const float* __restrict__ rW2, const float* __restrict__ rb2,
    float* __restrict__ agg)
{
    __shared__ float hT[64][68];
    __shared__ float tpw[64][132];
    __shared__ float xs_s[64][32];
    __shared__ float xv_s[64][48];
    __shared__ float dv_s[64][16];
    __shared__ float sh0_s[64];
    __shared__ float shv_s[64][3];
    __shared__ int   dst_s[64];
    __shared__ float msg[64][84];

    const int t  = threadIdx.x;
    const int e0 = blockIdx.x * 64;
    if (t < 64) {
        const int eid = e0 + t;
        dst_s[t] = ei[N_EDGES_C + eid];
        const float4 s4 = *reinterpret_cast<const float4*>(sh + (size_t)eid * 4);
        sh0_s[t] = s4.x; shv_s[t][0] = s4.y; shv_s[t][1] = s4.z; shv_s[t][2] = s4.w;
    }
    for (int i = t; i < 64 * 84; i += 256) (&msg[0][0])[i] = 0.0f;
    {
        const int e = t >> 2, q = t & 3;
        const int src = ei[e0 + e];
        const float* p = nf + (size_t)src * 80 + q * 20;
        #pragma unroll
        for (int f4 = 0; f4 < 5; f4++) {
            const float4 v = *reinterpret_cast<const float4*>(p + f4 * 4);
            const int g = q * 20 + f4 * 4;
            const float vv[4] = {v.x, v.y, v.z, v.w};
            #pragma unroll
            for (int ii = 0; ii < 4; ii++) {
                const int gg = g + ii;
                if (gg < 32) xs_s[e][gg] = vv[ii]; else xv_s[e][gg - 32] = vv[ii];
            }
        }
    }
    {
        const int c = t & 63, eg = t >> 6;
        float w1[8];
        #pragma unroll
        for (int b = 0; b < 8; b++) w1[b] = rW1[b * 64 + c];
        const float bias = rb1[c];
        #pragma unroll
        for (int rep = 0; rep < 16; rep++) {
            const int e = rep * 4 + eg;
            const float* em = emb + (size_t)(e0 + e) * 8;
            float pre = bias;
            #pragma unroll
            for (int b = 0; b < 8; b++) pre = fmaf(em[b], w1[b], pre);
            hT[c][e] = silu_f(pre);
        }
    }
    __syncthreads();
    {
        const int e = t >> 2, q = t & 3;
        #pragma unroll
        for (int i = 0; i < 4; i++) {
            const int u = q * 4 + i;
            dv_s[e][u] = xv_s[e][u*3+0]*shv_s[e][0] + xv_s[e][u*3+1]*shv_s[e][1]
                       + xv_s[e][u*3+2]*shv_s[e][2];
        }
    }
    __syncthreads();
    const int lane = t & 63, wv = t >> 6;
    for (int ch = 0; ch < 18; ch++) {
        const int jb = ch * 128;
        float acc[16][2];
        #pragma unroll
        for (int i = 0; i < 16; i++) { acc[i][0] = 0.0f; acc[i][1] = 0.0f; }
        const float* Bp = rW2 + jb + lane * 2;
        #pragma unroll 2
        for (int c = 0; c < 64; c++) {
            const float2 b = *reinterpret_cast<const float2*>(Bp + (size_t)c * 2304);
            const float4* ap = reinterpret_cast<const float4*>(&hT[c][wv * 16]);
            const float4 a0 = ap[0], a1 = ap[1], a2 = ap[2], a3 = ap[3];
            const float va[16] = {a0.x,a0.y,a0.z,a0.w, a1.x,a1.y,a1.z,a1.w,
                                  a2.x,a2.y,a2.z,a2.w, a3.x,a3.y,a3.z,a3.w};
            #pragma unroll
            for (int i = 0; i < 16; i++) {
                acc[i][0] = fmaf(va[i], b.x, acc[i][0]);
                acc[i][1] = fmaf(va[i], b.y, acc[i][1]);
            }
        }
        const float2 rb = *reinterpret_cast<const float2*>(rb2 + jb + lane * 2);
        __syncthreads();
        #pragma unroll
        for (int i = 0; i < 16; i++)
            *reinterpret_cast<float2*>(&tpw[wv * 16 + i][lane * 2]) =
                make_float2(acc[i][0] + rb.x, acc[i][1] + rb.y);
        __syncthreads();
        if (ch < 8) {
            const int u0 = ch * 4, w = t & 31, eg = t >> 5;
            #pragma unroll
            for (int ee = 0; ee < 8; ee++) {
                const int e = eg * 8 + ee;
                float s = 0.0f;
                #pragma unroll
                for (int du = 0; du < 4; du++) s = fmaf(tpw[e][du * 32 + w], xs_s[e][u0 + du], s);
                msg[e][w] = fmaf(PW0_C * sh0_s[e], s, msg[e][w]);
            }
        } else if (ch < 12) {
            const int u0 = (ch - 8) * 8, w = t & 15, eg = t >> 4;
            #pragma unroll
            for (int ee = 0; ee < 4; ee++) {
                const int e = eg * 4 + ee;
                float s = 0.0f;
                #pragma unroll
                for (int du = 0; du < 8; du++) s = fmaf(tpw[e][du * 16 + w], xs_s[e][u0 + du], s);
                const float c1s = C1_C * s;
                msg[e][32 + w*3 + 0] = fmaf(c1s, shv_s[e][0], msg[e][32 + w*3 + 0]);
                msg[e][32 + w*3 + 1] = fmaf(c1s, shv_s[e][1], msg[e][32 + w*3 + 1]);
                msg[e][32 + w*3 + 2] = fmaf(c1s, shv_s[e][2], msg[e][32 + w*3 + 2]);
            }
        } else if (ch < 14) {
            const int u0 = (ch - 12) * 8, w = t & 15, eg = t >> 4;
            #pragma unroll
            for (int ee = 0; ee < 4; ee++) {
                const int e = eg * 4 + ee;
                float s0 = 0, s1 = 0, s2 = 0;
                #pragma unroll
                for (int du = 0; du < 8; du++) {
                    const float tv = tpw[e][du * 16 + w];
                    const int u = u0 + du;
                    s0 = fmaf(tv, xv_s[e][u*3 + 0], s0);
                    s1 = fmaf(tv, xv_s[e][u*3 + 1], s1);
                    s2 = fmaf(tv, xv_s[e][u*3 + 2], s2);
                }
                const float f = C1_C * sh0_s[e];
                msg[e][32 + w*3 + 0] = fmaf(f, s0, msg[e][32 + w*3 + 0]);
                msg[e][32 + w*3 + 1] = fmaf(f, s1, msg[e][32 + w*3 + 1]);
                msg[e][32 + w*3 + 2] = fmaf(f, s2, msg[e][32 + w*3 + 2]);
            }
        } else {
            const int u0 = (ch - 14) * 4, w = t & 31, eg = t >> 5;
            #pragma unroll
            for (int ee = 0; ee < 8; ee++) {
                const int e = eg * 8 + ee;
                float s = 0.0f;
                #pragma unroll
                for (int du = 0; du < 4; du++) s = fmaf(tpw[e][du * 32 + w], dv_s[e][u0 + du], s);
                msg[e][w] = fmaf(PW0IS3_C, s, msg[e][w]);
            }
        }
    }
    __syncthreads();
    for (int i = t; i < 64 * 80; i += 256) {
        const int e = i / 80, m = i - e * 80;
        atomicAdd(&agg[(size_t)dst_s[e] * 80 + m], msg[e][m]);
    }
}

// Node update, IN PLACE on io (= d_out, holding agg).
__global__ __launch_bounds__(256, 4) void node_kernel(
    const float* __restrict__ nf,
    float* __restrict__ io,
    const float* __restrict__ Wl0,
    const float* __restrict__ Wl1)
{
    __shared__ float a_s[4][80];
    const int t  = threadIdx.x;
    const int nb = blockIdx.x * 4;
    for (int i = t; i < 320; i += 256)
        a_s[i / 80][i % 80] = io[(size_t)nb * 80 + i];
    __syncthreads();

    const int ln = t >> 6;
    const int r  = t & 63;
    const int n  = nb + ln;
    const float* a = a_s[ln];
    if (r < 32) {
        float s = 0.0f;
        #pragma unroll
        for (int u = 0; u < 32; u++) s = fmaf(a[u], Wl0[u * 32 + r], s);
        s *= RS32_C;
        io[(size_t)n * 80 + r] = nf[(size_t)n * 80 + r] + silu_f(s);
    } else if (r < 48) {
        const int v = r - 32;
        float l0 = 0, l1 = 0, l2 = 0;
        #pragma unroll
        for (int u = 0; u < 16; u++) {
            const float w = Wl1[u * 16 + v];
            l0 = fmaf(a[32 + u*3 + 0], w, l0);
            l1 = fmaf(a[32 + u*3 + 1], w, l1);
            l2 = fmaf(a[32 + u*3 + 2], w, l2);
        }
        l0 *= 0.25f; l1 *= 0.25f; l2 *= 0.25f;
        const float norm = sqrtf(l0*l0 + l1*l1 + l2*l2);
        float f = 0.0f;
        if (norm >= 1e-8f) f = silu_f(norm) / norm;
        const size_t o = (size_t)n * 80 + 32 + (size_t)v * 3;
        io[o + 0] = nf[o + 0] + f * l0;
        io[o + 1] = nf[o + 1] + f * l1;
        io[o + 2] = nf[o + 2] + f * l2;
    }
}

extern "C" void kernel_launch(void* const* d_in, const int* in_sizes, int n_in,
                              void* d_out, int out_size, void* d_ws, size_t ws_size,
                              hipStream_t stream) {
    const float* nf  = (const float*)d_in[0];
    const int*   ei  = (const int*)d_in[1];
    const float* sh  = (const float*)d_in[2];
    const float* emb = (const float*)d_in[3];
    const float* rW1 = (const float*)d_in[4];
    const float* rb1 = (const float*)d_in[5];
    const float* rW2 = (const float*)d_in[6];
    const float* rb2 = (const float*)d_in[7];
    const float* Wl0 = (const float*)d_in[8];
    const float* Wl1 = (const float*)d_in[9];

    float* agg = (float*)d_out;
    hipMemsetAsync(agg, 0, (size_t)N_NODES_C * 80 * sizeof(float), stream);

    const size_t rW2T_bytes = (size_t)2304 * 64 * sizeof(unsigned short);
    if (d_ws != nullptr && ws_size >= rW2T_bytes) {
        unsigned short* rW2T = (unsigned short*)d_ws;
        prep_kernel<<<(2304 * 64) / 256, 256, 0, stream>>>(rW2, rW2T);
        edge_kernel_mfma<<<N_EDGES_C / 64, 256, 0, stream>>>(
            nf, ei, sh, emb, rW1, rb1, rW2T, rb2, agg);
    } else {
        edge_kernel_f32<<<N_EDGES_C / 64, 256, 0, stream>>>(
            nf, ei, sh, emb, rW1, rb1, rW2, rb2, agg);
    }
    node_kernel<<<N_NODES_C / 4, 256, 0, stream>>>(nf, agg, Wl0, Wl1);
}